// Round 8
// baseline (84.250 us; speedup 1.0000x reference)
//
#include <hip/hip_runtime.h>
#include <math.h>

// out = |<psi(x2), psi(x1)>|^2, psi(x) = U(x,w)|0> (forward circuit only).
// STATE-SPLIT layout: each lane simulates ONE state (16 complex amps in reg).
// Wave = 64 lanes: lanes 0..31 run psi(x1) for elements e..e+31, lanes 32..63
// run psi(x2) for the same elements. Final dot via one __shfl_xor(.,32).
// 4-qubit statevector; qubit q = bit (3-q). State = f2 (re,im) per amplitude.

#define DEVI static __device__ __forceinline__

typedef float f2 __attribute__((ext_vector_type(2)));

DEVI f2 sp(float x) { f2 r; r.x = x; r.y = x; return r; }
DEVI f2 mk(float x, float y) { f2 r; r.x = x; r.y = y; return r; }
DEVI f2 fm(f2 a, f2 b, f2 c) { return __builtin_elementwise_fma(a, b, c); }
DEVI f2 nI(f2 a) { f2 r; r.x = a.y;  r.y = -a.x; return r; }   // -i*a
DEVI f2 pI(f2 a) { f2 r; r.x = -a.y; r.y = a.x;  return r; }   // +i*a
// a * g for uniform complex g, with ig = i*g precomputed: 2 packed insts
DEVI f2 cmulc(f2 a, f2 g, f2 ig) { return fm(sp(a.y), ig, sp(a.x) * g); }

// ---------------- gate helpers (one 16-amp state) ----------------

template<int Q> DEVI void gX(f2* v) {
  constexpr int m = 1 << (3 - Q);
#pragma unroll
  for (int i = 0; i < 16; ++i) if (!(i & m)) {
    const int j = i | m; f2 t = v[i]; v[i] = v[j]; v[j] = t;
  }
}

// RY(t): [[c,-s],[s,c]]
template<int Q> DEVI void gRY(f2* v, float c, float s) {
  constexpr int m = 1 << (3 - Q);
  const f2 C = sp(c), S = sp(s), NS = sp(-s);
#pragma unroll
  for (int i = 0; i < 16; ++i) if (!(i & m)) {
    const int j = i | m;
    f2 a = v[i], b = v[j];
    v[i] = fm(b, NS, a * C);
    v[j] = fm(b, C,  a * S);
  }
}

// RX(t): [[c,-is],[-is,c]]
template<int Q> DEVI void gRX(f2* v, float c, float s) {
  constexpr int m = 1 << (3 - Q);
  const f2 C = sp(c), S = sp(s);
#pragma unroll
  for (int i = 0; i < 16; ++i) if (!(i & m)) {
    const int j = i | m;
    f2 a = v[i], b = v[j];
    v[i] = fm(nI(b), S, a * C);
    v[j] = fm(nI(a), S, b * C);
  }
}

// RZ(t): diag(c-is, c+is)
template<int Q> DEVI void gRZ(f2* v, float c, float s) {
  constexpr int m = 1 << (3 - Q);
  const f2 g0 = mk(c, -s), ig0 = mk(s, c);
  const f2 g1 = mk(c,  s), ig1 = mk(-s, c);
#pragma unroll
  for (int i = 0; i < 16; ++i) {
    f2 a = v[i];
    v[i] = (i & m) ? cmulc(a, g1, ig1) : cmulc(a, g0, ig0);
  }
}

// H*RX(w): [[Em,Em],[Ep,-Ep]]
template<int Q> DEVI void gHRX(f2* v, f2 Em, f2 Ep, f2 iEm, f2 iEp) {
  constexpr int m = 1 << (3 - Q);
#pragma unroll
  for (int i = 0; i < 16; ++i) if (!(i & m)) {
    const int j = i | m;
    f2 a = v[i], b = v[j];
    f2 t = a + b, u = a - b;
    v[i] = cmulc(t, Em, iEm);
    v[j] = cmulc(u, Ep, iEp);
  }
}

// H*RZ(w): [[Em,Ep],[Em,-Ep]]
template<int Q> DEVI void gHRZ(f2* v, f2 Em, f2 Ep, f2 iEm, f2 iEp) {
  constexpr int m = 1 << (3 - Q);
#pragma unroll
  for (int i = 0; i < 16; ++i) if (!(i & m)) {
    const int j = i | m;
    f2 a = v[i], b = v[j];
    f2 p = cmulc(a, Em, iEm), q = cmulc(b, Ep, iEp);
    v[i] = p + q;
    v[j] = p - q;
  }
}

// Y*RZ(w): [[0,G1],[G2,0]]
template<int Q> DEVI void gYRZ(f2* v, f2 G1, f2 G2, f2 iG1, f2 iG2) {
  constexpr int m = 1 << (3 - Q);
#pragma unroll
  for (int i = 0; i < 16; ++i) if (!(i & m)) {
    const int j = i | m;
    f2 a = v[i], b = v[j];
    v[i] = cmulc(b, G1, iG1);
    v[j] = cmulc(a, G2, iG2);
  }
}

// Y*RX(w): out_i = -s*a + c*(-i b); out_j = c*(i a) + s*b
template<int Q> DEVI void gYRX(f2* v, float c, float s) {
  constexpr int m = 1 << (3 - Q);
  const f2 C = sp(c), S = sp(s), NS = sp(-s);
#pragma unroll
  for (int i = 0; i < 16; ++i) if (!(i & m)) {
    const int j = i | m;
    f2 a = v[i], b = v[j];
    v[i] = fm(nI(b), C, a * NS);
    v[j] = fm(pI(a), C, b * S);
  }
}

// Z*RX(w): out_i = c*a + s*(-i b); out_j = s*(i a) - c*b
template<int Q> DEVI void gZRX(f2* v, float c, float s) {
  constexpr int m = 1 << (3 - Q);
  const f2 C = sp(c), S = sp(s), NC = sp(-c);
#pragma unroll
  for (int i = 0; i < 16; ++i) if (!(i & m)) {
    const int j = i | m;
    f2 a = v[i], b = v[j];
    v[i] = fm(nI(b), S, a * C);
    v[j] = fm(pI(a), S, b * NC);
  }
}

// Z*RZ(w): bit0 -> a*(c-is); bit1 -> a*(-c-is)
template<int Q> DEVI void gZRZ(f2* v, float c, float s) {
  constexpr int m = 1 << (3 - Q);
  const f2 g0 = mk(c, -s),  ig0 = mk(s, c);
  const f2 g1 = mk(-c, -s), ig1 = mk(s, -c);
#pragma unroll
  for (int i = 0; i < 16; ++i) {
    f2 a = v[i];
    v[i] = (i & m) ? cmulc(a, g1, ig1) : cmulc(a, g0, ig0);
  }
}

// Z*RY(w): out_i = c*a - s*b; out_j = -s*a - c*b
template<int Q> DEVI void gZRY(f2* v, float c, float s) {
  constexpr int m = 1 << (3 - Q);
  const f2 C = sp(c), NS = sp(-s), NC = sp(-c);
#pragma unroll
  for (int i = 0; i < 16; ++i) if (!(i & m)) {
    const int j = i | m;
    f2 a = v[i], b = v[j];
    v[i] = fm(b, NS, a * C);
    v[j] = fm(b, NC, a * NS);
  }
}

// H*RY(phi): K[[c+s, c-s],[c-s, -(c+s)]]
template<int Q> DEVI void gHRY(f2* v, float c, float s) {
  constexpr int m = 1 << (3 - Q);
  const float K = 0.70710678118654752440f;
  const float al = K * (c + s), be = K * (c - s);
  const f2 AL = sp(al), BE = sp(be), NAL = sp(-al);
#pragma unroll
  for (int i = 0; i < 16; ++i) if (!(i & m)) {
    const int j = i | m;
    f2 a = v[i], b = v[j];
    v[i] = fm(b, BE,  a * AL);
    v[j] = fm(b, NAL, a * BE);
  }
}

// Y*RY(phi): out_i = -i(s*a + c*b); out_j = i(c*a - s*b)
template<int Q> DEVI void gYRY(f2* v, float c, float s) {
  constexpr int m = 1 << (3 - Q);
  const f2 C = sp(c), S = sp(s), NS = sp(-s);
#pragma unroll
  for (int i = 0; i < 16; ++i) if (!(i & m)) {
    const int j = i | m;
    f2 a = v[i], b = v[j];
    f2 t = fm(b, C, a * S);
    f2 u = fm(b, NS, a * C);
    v[i] = nI(t);
    v[j] = pI(u);
  }
}

template<int A, int B2> DEVI void gCZ(f2* v) {
  constexpr int ma = 1 << (3 - A), mb = 1 << (3 - B2);
#pragma unroll
  for (int i = 0; i < 16; ++i) if ((i & ma) && (i & mb)) v[i] = -v[i];
}

template<int C, int T> DEVI void gCNOT(f2* v) {
  constexpr int mc = 1 << (3 - C), mt = 1 << (3 - T);
#pragma unroll
  for (int i = 0; i < 16; ++i) if ((i & mc) && !(i & mt)) {
    const int j = i | mt; f2 t = v[i]; v[i] = v[j]; v[j] = t;
  }
}

template<int C1, int C2, int T> DEVI void gTOF(f2* v) {
  constexpr int m1 = 1 << (3 - C1), m2 = 1 << (3 - C2), mt = 1 << (3 - T);
#pragma unroll
  for (int i = 0; i < 16; ++i) if ((i & m1) && (i & m2) && !(i & mt)) {
    const int j = i | mt; f2 t = v[i]; v[i] = v[j]; v[j] = t;
  }
}

template<int C, int A, int B2> DEVI void gCSWAP(f2* v) {
  constexpr int mc = 1 << (3 - C), ma = 1 << (3 - A), mb = 1 << (3 - B2);
#pragma unroll
  for (int i = 0; i < 16; ++i) if ((i & mc) && (i & ma) && !(i & mb)) {
    const int j = (i ^ ma) | mb; f2 t = v[i]; v[i] = v[j]; v[j] = t;
  }
}

// forward circuit: v starts at H^4|0> = uniform 1/4 (identical to verified r5)
DEVI void fwd(f2* v, const float* cx, const float* sx,
              const float* cw, const float* sw) {
  const float K = 0.70710678118654752440f;
  const f2 Em0  = mk(K*cw[0], -K*sw[0]), Ep0  = mk(K*cw[0],  K*sw[0]);
  const f2 iEm0 = mk(K*sw[0],  K*cw[0]), iEp0 = mk(-K*sw[0], K*cw[0]);
  const f2 G1   = mk(sw[2], -cw[2]),     G2   = mk(sw[2],  cw[2]);
  const f2 iG1  = mk(cw[2],  sw[2]),     iG2  = mk(-cw[2], sw[2]);
  const f2 Em8  = mk(K*cw[8], -K*sw[8]), Ep8  = mk(K*cw[8],  K*sw[8]);
  const f2 iEm8 = mk(K*sw[8],  K*cw[8]), iEp8 = mk(-K*sw[8], K*cw[8]);
  // fused RY(x)*RY(w) half-angle sums at l+n==4 sites
  const float c73  = cx[3]*cw[7]  - sx[3]*sw[7],  s73  = sx[3]*cw[7]  + cx[3]*sw[7];
  const float c102 = cx[2]*cw[10] - sx[2]*sw[10], s102 = sx[2]*cw[10] + cx[2]*sw[10];
  const float c131 = cx[1]*cw[13] - sx[1]*sw[13], s131 = sx[1]*cw[13] + cx[1]*sw[13];
  const float c160 = cx[0]*cw[16] - sx[0]*sw[16], s160 = sx[0]*cw[16] + cx[0]*sw[16];

  // l=0
  gRY<0>(v, cx[0], sx[0]); gHRX<0>(v, Em0, Ep0, iEm0, iEp0);
  gRY<1>(v, cw[1], sw[1]); gX<1>(v);
  gRY<2>(v, cx[2], sx[2]); gYRZ<2>(v, G1, G2, iG1, iG2);
  gZRX<3>(v, cw[3], sw[3]);
  // l=1
  gRY<0>(v, cw[4], sw[4]); gCNOT<0,1>(v);
  gRY<1>(v, cx[1], sx[1]); gRZ<1>(v, cw[5], sw[5]); gCZ<1,2>(v);
  gRX<2>(v, cw[6], sw[6]); gTOF<2,3,0>(v);
  gRY<3>(v, c73, s73);     gCSWAP<3,0,1>(v);
  // l=2
  gRY<0>(v, cx[0], sx[0]); gHRZ<0>(v, Em8, Ep8, iEm8, iEp8);
  gRX<1>(v, cw[9], sw[9]); gX<1>(v);
  gYRY<2>(v, c102, s102);
  gZRZ<3>(v, cw[11], sw[11]);
  // l=3
  gRX<0>(v, cw[12], sw[12]); gCNOT<0,1>(v);
  gRY<1>(v, c131, s131);     gCZ<1,2>(v);
  gRZ<2>(v, cw[14], sw[14]); gTOF<2,3,0>(v);
  gRY<3>(v, cx[3], sx[3]); gRX<3>(v, cw[15], sw[15]); gCSWAP<3,0,1>(v);
  // l=4
  gHRY<0>(v, c160, s160);
  gRZ<1>(v, cw[17], sw[17]); gX<1>(v);
  gRY<2>(v, cx[2], sx[2]); gYRX<2>(v, cw[18], sw[18]);
  gZRY<3>(v, cw[19], sw[19]);
  // l=5
  gRZ<0>(v, cw[20], sw[20]); gCNOT<0,1>(v);
  gRY<1>(v, cx[1], sx[1]); gRX<1>(v, cw[21], sw[21]); gCZ<1,2>(v);
  gRY<2>(v, cw[22], sw[22]); gTOF<2,3,0>(v);
  gRY<3>(v, cx[3], sx[3]); gRZ<3>(v, cw[23], sw[23]); gCSWAP<3,0,1>(v);
}

DEVI float rlane(float v, int l) {
  return __int_as_float(__builtin_amdgcn_readlane(__float_as_int(v), l));
}

__global__ __launch_bounds__(256, 6)
void qsim(const float* __restrict__ x1, const float* __restrict__ x2,
          const float* __restrict__ q, float* __restrict__ out, int B)
{
  const int t = blockIdx.x * blockDim.x + threadIdx.x;
  const int lane = threadIdx.x & 63;
  const int half = lane >> 5;            // 0: x1-state, 1: x2-state
  const int j = lane & 31;
  const int e = (t >> 6) * 32 + j;       // element id
  if (e >= B) return;

  // batch-uniform w sincos: lanes 0..23 compute, broadcast via readlane -> SGPR
  float qv = 0.f;
  if (lane < 24) qv = q[lane];
  float mys, myc;
  __sincosf(0.5f * qv, &mys, &myc);
  float cw[24], sw[24];
#pragma unroll
  for (int k = 0; k < 24; ++k) { cw[k] = rlane(myc, k); sw[k] = rlane(mys, k); }

  // per-lane x: half-wave-coalesced float4 loads
  const float4 xv = half ? reinterpret_cast<const float4*>(x2)[e]
                         : reinterpret_cast<const float4*>(x1)[e];
  float cx[4], sx[4];
  __sincosf(0.5f * xv.x, &sx[0], &cx[0]);
  __sincosf(0.5f * xv.y, &sx[1], &cx[1]);
  __sincosf(0.5f * xv.z, &sx[2], &cx[2]);
  __sincosf(0.5f * xv.w, &sx[3], &cx[3]);

  // state starts at H^4|0> = uniform 1/4
  f2 v[16];
#pragma unroll
  for (int i = 0; i < 16; ++i) v[i] = mk(0.25f, 0.f);

  fwd(v, cx, sx, cw, sw);

  // exchange amps with the opposite half-wave (partner lane = lane ^ 32)
  f2 o[16];
#pragma unroll
  for (int i = 0; i < 16; ++i) {
    o[i].x = __shfl_xor(v[i].x, 32, 64);
    o[i].y = __shfl_xor(v[i].y, 32, 64);
  }

  // dot = sum_i conj(o_i) * v_i  (lanes>=32 get the conjugate -> same |.|^2)
  f2 acc = mk(0.f, 0.f);   // (re, im)
#pragma unroll
  for (int i = 0; i < 16; ++i) {
    f2 t1 = mk(v[i].x, v[i].y) * sp(o[i].x);     // (Bx*Ax, Bx*Ay)
    f2 t2 = mk(v[i].y, -v[i].x) * sp(o[i].y);    // (By*Ay, -By*Ax)
    acc = acc + t1 + t2;
  }
  if (!half) out[e] = acc.x * acc.x + acc.y * acc.y;
}

extern "C" void kernel_launch(void* const* d_in, const int* in_sizes, int n_in,
                              void* d_out, int out_size, void* d_ws, size_t ws_size,
                              hipStream_t stream) {
  const float* x1 = (const float*)d_in[0];
  const float* x2 = (const float*)d_in[1];
  const float* q  = (const float*)d_in[2];
  float* out = (float*)d_out;
  const int B = in_sizes[0] / 4;
  const int block = 256;
  const long long threads = 2LL * B;     // one lane per (element, state)
  const int grid = (int)((threads + block - 1) / block);
  qsim<<<grid, block, 0, stream>>>(x1, x2, q, out, B);
}

// Round 11
// 79.221 us; speedup vs baseline: 1.0635x; 1.0635x over previous
//
#include <hip/hip_runtime.h>
#include <math.h>

// out = |<psi(x2), psi(x1)>|^2, psi(x) = U(x,w)|0> (forward circuit only).
// STATE-SPLIT layout: each lane simulates ONE state (16 complex amps in reg).
// Wave = 64 lanes: lanes 0..31 run psi(x1) for elements e..e+31, lanes 32..63
// run psi(x2) for the same elements. Final dot via __shfl_xor(.,32) interleaved
// with the accumulation (low register pressure).
// NOTE r8 lesson: __launch_bounds__(256,6) forced 40-VGPR cap -> statevector
// spilled to scratch (WRITE_SIZE 41MB vs 1MB ideal). Use (256,4): 128-VGPR cap.

#define DEVI static __device__ __forceinline__

typedef float f2 __attribute__((ext_vector_type(2)));

DEVI f2 sp(float x) { f2 r; r.x = x; r.y = x; return r; }
DEVI f2 mk(float x, float y) { f2 r; r.x = x; r.y = y; return r; }
DEVI f2 fm(f2 a, f2 b, f2 c) { return __builtin_elementwise_fma(a, b, c); }
DEVI f2 nI(f2 a) { f2 r; r.x = a.y;  r.y = -a.x; return r; }   // -i*a
DEVI f2 pI(f2 a) { f2 r; r.x = -a.y; r.y = a.x;  return r; }   // +i*a
// a * g for uniform complex g, with ig = i*g precomputed: 2 packed insts
DEVI f2 cmulc(f2 a, f2 g, f2 ig) { return fm(sp(a.y), ig, sp(a.x) * g); }

// ---------------- gate helpers (one 16-amp state) ----------------

template<int Q> DEVI void gX(f2* v) {
  constexpr int m = 1 << (3 - Q);
#pragma unroll
  for (int i = 0; i < 16; ++i) if (!(i & m)) {
    const int j = i | m; f2 t = v[i]; v[i] = v[j]; v[j] = t;
  }
}

// RY(t): [[c,-s],[s,c]]
template<int Q> DEVI void gRY(f2* v, float c, float s) {
  constexpr int m = 1 << (3 - Q);
  const f2 C = sp(c), S = sp(s), NS = sp(-s);
#pragma unroll
  for (int i = 0; i < 16; ++i) if (!(i & m)) {
    const int j = i | m;
    f2 a = v[i], b = v[j];
    v[i] = fm(b, NS, a * C);
    v[j] = fm(b, C,  a * S);
  }
}

// RX(t): [[c,-is],[-is,c]]
template<int Q> DEVI void gRX(f2* v, float c, float s) {
  constexpr int m = 1 << (3 - Q);
  const f2 C = sp(c), S = sp(s);
#pragma unroll
  for (int i = 0; i < 16; ++i) if (!(i & m)) {
    const int j = i | m;
    f2 a = v[i], b = v[j];
    v[i] = fm(nI(b), S, a * C);
    v[j] = fm(nI(a), S, b * C);
  }
}

// RZ(t): diag(c-is, c+is)
template<int Q> DEVI void gRZ(f2* v, float c, float s) {
  constexpr int m = 1 << (3 - Q);
  const f2 g0 = mk(c, -s), ig0 = mk(s, c);
  const f2 g1 = mk(c,  s), ig1 = mk(-s, c);
#pragma unroll
  for (int i = 0; i < 16; ++i) {
    f2 a = v[i];
    v[i] = (i & m) ? cmulc(a, g1, ig1) : cmulc(a, g0, ig0);
  }
}

// H*RX(w): [[Em,Em],[Ep,-Ep]]
template<int Q> DEVI void gHRX(f2* v, f2 Em, f2 Ep, f2 iEm, f2 iEp) {
  constexpr int m = 1 << (3 - Q);
#pragma unroll
  for (int i = 0; i < 16; ++i) if (!(i & m)) {
    const int j = i | m;
    f2 a = v[i], b = v[j];
    f2 t = a + b, u = a - b;
    v[i] = cmulc(t, Em, iEm);
    v[j] = cmulc(u, Ep, iEp);
  }
}

// H*RZ(w): [[Em,Ep],[Em,-Ep]]
template<int Q> DEVI void gHRZ(f2* v, f2 Em, f2 Ep, f2 iEm, f2 iEp) {
  constexpr int m = 1 << (3 - Q);
#pragma unroll
  for (int i = 0; i < 16; ++i) if (!(i & m)) {
    const int j = i | m;
    f2 a = v[i], b = v[j];
    f2 p = cmulc(a, Em, iEm), q = cmulc(b, Ep, iEp);
    v[i] = p + q;
    v[j] = p - q;
  }
}

// Y*RZ(w): [[0,G1],[G2,0]]
template<int Q> DEVI void gYRZ(f2* v, f2 G1, f2 G2, f2 iG1, f2 iG2) {
  constexpr int m = 1 << (3 - Q);
#pragma unroll
  for (int i = 0; i < 16; ++i) if (!(i & m)) {
    const int j = i | m;
    f2 a = v[i], b = v[j];
    v[i] = cmulc(b, G1, iG1);
    v[j] = cmulc(a, G2, iG2);
  }
}

// Y*RX(w): out_i = -s*a + c*(-i b); out_j = c*(i a) + s*b
template<int Q> DEVI void gYRX(f2* v, float c, float s) {
  constexpr int m = 1 << (3 - Q);
  const f2 C = sp(c), S = sp(s), NS = sp(-s);
#pragma unroll
  for (int i = 0; i < 16; ++i) if (!(i & m)) {
    const int j = i | m;
    f2 a = v[i], b = v[j];
    v[i] = fm(nI(b), C, a * NS);
    v[j] = fm(pI(a), C, b * S);
  }
}

// Z*RX(w): out_i = c*a + s*(-i b); out_j = s*(i a) - c*b
template<int Q> DEVI void gZRX(f2* v, float c, float s) {
  constexpr int m = 1 << (3 - Q);
  const f2 C = sp(c), S = sp(s), NC = sp(-c);
#pragma unroll
  for (int i = 0; i < 16; ++i) if (!(i & m)) {
    const int j = i | m;
    f2 a = v[i], b = v[j];
    v[i] = fm(nI(b), S, a * C);
    v[j] = fm(pI(a), S, b * NC);
  }
}

// Z*RZ(w): bit0 -> a*(c-is); bit1 -> a*(-c-is)
template<int Q> DEVI void gZRZ(f2* v, float c, float s) {
  constexpr int m = 1 << (3 - Q);
  const f2 g0 = mk(c, -s),  ig0 = mk(s, c);
  const f2 g1 = mk(-c, -s), ig1 = mk(s, -c);
#pragma unroll
  for (int i = 0; i < 16; ++i) {
    f2 a = v[i];
    v[i] = (i & m) ? cmulc(a, g1, ig1) : cmulc(a, g0, ig0);
  }
}

// Z*RY(w): out_i = c*a - s*b; out_j = -s*a - c*b
template<int Q> DEVI void gZRY(f2* v, float c, float s) {
  constexpr int m = 1 << (3 - Q);
  const f2 C = sp(c), NS = sp(-s), NC = sp(-c);
#pragma unroll
  for (int i = 0; i < 16; ++i) if (!(i & m)) {
    const int j = i | m;
    f2 a = v[i], b = v[j];
    v[i] = fm(b, NS, a * C);
    v[j] = fm(b, NC, a * NS);
  }
}

// H*RY(phi): K[[c+s, c-s],[c-s, -(c+s)]]
template<int Q> DEVI void gHRY(f2* v, float c, float s) {
  constexpr int m = 1 << (3 - Q);
  const float K = 0.70710678118654752440f;
  const float al = K * (c + s), be = K * (c - s);
  const f2 AL = sp(al), BE = sp(be), NAL = sp(-al);
#pragma unroll
  for (int i = 0; i < 16; ++i) if (!(i & m)) {
    const int j = i | m;
    f2 a = v[i], b = v[j];
    v[i] = fm(b, BE,  a * AL);
    v[j] = fm(b, NAL, a * BE);
  }
}

// Y*RY(phi): out_i = -i(s*a + c*b); out_j = i(c*a - s*b)
template<int Q> DEVI void gYRY(f2* v, float c, float s) {
  constexpr int m = 1 << (3 - Q);
  const f2 C = sp(c), S = sp(s), NS = sp(-s);
#pragma unroll
  for (int i = 0; i < 16; ++i) if (!(i & m)) {
    const int j = i | m;
    f2 a = v[i], b = v[j];
    f2 t = fm(b, C, a * S);
    f2 u = fm(b, NS, a * C);
    v[i] = nI(t);
    v[j] = pI(u);
  }
}

template<int A, int B2> DEVI void gCZ(f2* v) {
  constexpr int ma = 1 << (3 - A), mb = 1 << (3 - B2);
#pragma unroll
  for (int i = 0; i < 16; ++i) if ((i & ma) && (i & mb)) v[i] = -v[i];
}

template<int C, int T> DEVI void gCNOT(f2* v) {
  constexpr int mc = 1 << (3 - C), mt = 1 << (3 - T);
#pragma unroll
  for (int i = 0; i < 16; ++i) if ((i & mc) && !(i & mt)) {
    const int j = i | mt; f2 t = v[i]; v[i] = v[j]; v[j] = t;
  }
}

template<int C1, int C2, int T> DEVI void gTOF(f2* v) {
  constexpr int m1 = 1 << (3 - C1), m2 = 1 << (3 - C2), mt = 1 << (3 - T);
#pragma unroll
  for (int i = 0; i < 16; ++i) if ((i & m1) && (i & m2) && !(i & mt)) {
    const int j = i | mt; f2 t = v[i]; v[i] = v[j]; v[j] = t;
  }
}

template<int C, int A, int B2> DEVI void gCSWAP(f2* v) {
  constexpr int mc = 1 << (3 - C), ma = 1 << (3 - A), mb = 1 << (3 - B2);
#pragma unroll
  for (int i = 0; i < 16; ++i) if ((i & mc) && (i & ma) && !(i & mb)) {
    const int j = (i ^ ma) | mb; f2 t = v[i]; v[i] = v[j]; v[j] = t;
  }
}

// forward circuit: v starts at H^4|0> = uniform 1/4 (identical to verified r5)
DEVI void fwd(f2* v, const float* cx, const float* sx,
              const float* cw, const float* sw) {
  const float K = 0.70710678118654752440f;
  const f2 Em0  = mk(K*cw[0], -K*sw[0]), Ep0  = mk(K*cw[0],  K*sw[0]);
  const f2 iEm0 = mk(K*sw[0],  K*cw[0]), iEp0 = mk(-K*sw[0], K*cw[0]);
  const f2 G1   = mk(sw[2], -cw[2]),     G2   = mk(sw[2],  cw[2]);
  const f2 iG1  = mk(cw[2],  sw[2]),     iG2  = mk(-cw[2], sw[2]);
  const f2 Em8  = mk(K*cw[8], -K*sw[8]), Ep8  = mk(K*cw[8],  K*sw[8]);
  const f2 iEm8 = mk(K*sw[8],  K*cw[8]), iEp8 = mk(-K*sw[8], K*cw[8]);
  // fused RY(x)*RY(w) half-angle sums at l+n==4 sites
  const float c73  = cx[3]*cw[7]  - sx[3]*sw[7],  s73  = sx[3]*cw[7]  + cx[3]*sw[7];
  const float c102 = cx[2]*cw[10] - sx[2]*sw[10], s102 = sx[2]*cw[10] + cx[2]*sw[10];
  const float c131 = cx[1]*cw[13] - sx[1]*sw[13], s131 = sx[1]*cw[13] + cx[1]*sw[13];
  const float c160 = cx[0]*cw[16] - sx[0]*sw[16], s160 = sx[0]*cw[16] + cx[0]*sw[16];

  // l=0
  gRY<0>(v, cx[0], sx[0]); gHRX<0>(v, Em0, Ep0, iEm0, iEp0);
  gRY<1>(v, cw[1], sw[1]); gX<1>(v);
  gRY<2>(v, cx[2], sx[2]); gYRZ<2>(v, G1, G2, iG1, iG2);
  gZRX<3>(v, cw[3], sw[3]);
  // l=1
  gRY<0>(v, cw[4], sw[4]); gCNOT<0,1>(v);
  gRY<1>(v, cx[1], sx[1]); gRZ<1>(v, cw[5], sw[5]); gCZ<1,2>(v);
  gRX<2>(v, cw[6], sw[6]); gTOF<2,3,0>(v);
  gRY<3>(v, c73, s73);     gCSWAP<3,0,1>(v);
  // l=2
  gRY<0>(v, cx[0], sx[0]); gHRZ<0>(v, Em8, Ep8, iEm8, iEp8);
  gRX<1>(v, cw[9], sw[9]); gX<1>(v);
  gYRY<2>(v, c102, s102);
  gZRZ<3>(v, cw[11], sw[11]);
  // l=3
  gRX<0>(v, cw[12], sw[12]); gCNOT<0,1>(v);
  gRY<1>(v, c131, s131);     gCZ<1,2>(v);
  gRZ<2>(v, cw[14], sw[14]); gTOF<2,3,0>(v);
  gRY<3>(v, cx[3], sx[3]); gRX<3>(v, cw[15], sw[15]); gCSWAP<3,0,1>(v);
  // l=4
  gHRY<0>(v, c160, s160);
  gRZ<1>(v, cw[17], sw[17]); gX<1>(v);
  gRY<2>(v, cx[2], sx[2]); gYRX<2>(v, cw[18], sw[18]);
  gZRY<3>(v, cw[19], sw[19]);
  // l=5
  gRZ<0>(v, cw[20], sw[20]); gCNOT<0,1>(v);
  gRY<1>(v, cx[1], sx[1]); gRX<1>(v, cw[21], sw[21]); gCZ<1,2>(v);
  gRY<2>(v, cw[22], sw[22]); gTOF<2,3,0>(v);
  gRY<3>(v, cx[3], sx[3]); gRZ<3>(v, cw[23], sw[23]); gCSWAP<3,0,1>(v);
}

DEVI float rlane(float v, int l) {
  return __int_as_float(__builtin_amdgcn_readlane(__float_as_int(v), l));
}

__global__ __launch_bounds__(256, 4)
void qsim(const float* __restrict__ x1, const float* __restrict__ x2,
          const float* __restrict__ q, float* __restrict__ out, int B)
{
  const int t = blockIdx.x * blockDim.x + threadIdx.x;
  const int lane = threadIdx.x & 63;
  const int half = lane >> 5;            // 0: x1-state, 1: x2-state
  const int j = lane & 31;
  const int e = (t >> 6) * 32 + j;       // element id
  if (e >= B) return;

  // batch-uniform w sincos: lanes 0..23 compute, broadcast via readlane -> SGPR
  float qv = 0.f;
  if (lane < 24) qv = q[lane];
  float mys, myc;
  __sincosf(0.5f * qv, &mys, &myc);
  float cw[24], sw[24];
#pragma unroll
  for (int k = 0; k < 24; ++k) { cw[k] = rlane(myc, k); sw[k] = rlane(mys, k); }

  // per-lane x: half-wave-coalesced float4 loads
  const float4 xv = half ? reinterpret_cast<const float4*>(x2)[e]
                         : reinterpret_cast<const float4*>(x1)[e];
  float cx[4], sx[4];
  __sincosf(0.5f * xv.x, &sx[0], &cx[0]);
  __sincosf(0.5f * xv.y, &sx[1], &cx[1]);
  __sincosf(0.5f * xv.z, &sx[2], &cx[2]);
  __sincosf(0.5f * xv.w, &sx[3], &cx[3]);

  // state starts at H^4|0> = uniform 1/4
  f2 v[16];
#pragma unroll
  for (int i = 0; i < 16; ++i) v[i] = mk(0.25f, 0.f);

  fwd(v, cx, sx, cw, sw);

  // dot = sum_i conj(o_i) * v_i with o = partner half-wave's state
  // (lanes>=32 compute the conjugate -> same |.|^2). Shuffles interleaved
  // with accumulation: only 2 temps live at a time (r8: o[16] spilled).
  f2 acc = mk(0.f, 0.f);   // (re, im)
#pragma unroll
  for (int i = 0; i < 16; ++i) {
    const float ox = __shfl_xor(v[i].x, 32, 64);
    const float oy = __shfl_xor(v[i].y, 32, 64);
    f2 t1 = mk(v[i].x, v[i].y) * sp(ox);     // (Bx*Ax, Bx*Ay)
    f2 t2 = mk(v[i].y, -v[i].x) * sp(oy);    // (By*Ay, -By*Ax)
    acc = acc + t1 + t2;
  }
  if (!half) out[e] = acc.x * acc.x + acc.y * acc.y;
}

extern "C" void kernel_launch(void* const* d_in, const int* in_sizes, int n_in,
                              void* d_out, int out_size, void* d_ws, size_t ws_size,
                              hipStream_t stream) {
  const float* x1 = (const float*)d_in[0];
  const float* x2 = (const float*)d_in[1];
  const float* q  = (const float*)d_in[2];
  float* out = (float*)d_out;
  const int B = in_sizes[0] / 4;
  const int block = 256;
  const long long threads = 2LL * B;     // one lane per (element, state)
  const int grid = (int)((threads + block - 1) / block);
  qsim<<<grid, block, 0, stream>>>(x1, x2, q, out, B);
}